// Round 4
// baseline (1426.471 us; speedup 1.0000x reference)
//
#include <hip/hip_runtime.h>

constexpr int NNODES = 100000;
constexpr int NEDGES = 1280000;
constexpr int SCAN_ELEMS = 1024;
constexpr int NSCAN = (NNODES + SCAN_ELEMS - 1) / SCAN_ELEMS;  // 98

// ---------------------------------------------------------------------------
// Row-broadcast GEMM: C[r][lane] = sum_k X[r][k] * W[k][lane].
// lane = output column (64 cols); W column kept in VGPRs.
// Row index is wave-uniform (blockIdx + readfirstlane(wave)) so the X-row
// loads are emitted as scalar (SMEM) loads: no L1-return amplification,
// inner loop is v_fmac_f32 vacc, s[k], v_w[k].
// ---------------------------------------------------------------------------
__global__ __launch_bounds__(256) void gemm64_rows(
    const float* __restrict__ X,
    const float* __restrict__ W,
    float* __restrict__ C,
    int nrows)
{
    const int lane = threadIdx.x & 63;
    const int wvu  = __builtin_amdgcn_readfirstlane((int)(threadIdx.x >> 6));

    float w[64];
#pragma unroll
    for (int k = 0; k < 64; ++k) w[k] = W[k * 64 + lane];

    const int r0 = blockIdx.x * 128 + wvu * 32;
#pragma unroll 2
    for (int i = 0; i < 32; ++i) {
        const int r = r0 + i;               // wave-uniform
        if (r >= nrows) break;
        const float* __restrict__ xr = X + (size_t)r * 64;
        float acc = 0.f;
#pragma unroll
        for (int k = 0; k < 64; ++k) acc = fmaf(xr[k], w[k], acc);
        C[(size_t)r * 64 + lane] = acc;
    }
}

// ---------------------------------------------------------------------------
// Node projection, 3 sources fused, same scalar-broadcast structure.
// Processes rows in chunks of 8 (acc[8] statically indexed), reloading the
// weight column per (chunk, source) to keep VGPRs ~85.
// out = (XF@Wi + XR@Wo + XN@diag(lr)Wl) / 3 + bias
// All pointers strictly non-aliasing (accs live in workspace).
// ---------------------------------------------------------------------------
__global__ __launch_bounds__(256) void node_gemm3(
    const float* __restrict__ XF,
    const float* __restrict__ XR,
    const float* __restrict__ XN,
    const float* __restrict__ Wi,
    const float* __restrict__ Wo,
    const float* __restrict__ Wl,
    const float* __restrict__ lr,
    const float* __restrict__ bias,
    float* __restrict__ C,
    int nrows)
{
    const int lane = threadIdx.x & 63;
    const int wvu  = __builtin_amdgcn_readfirstlane((int)(threadIdx.x >> 6));
    const float b = bias[lane];
    const int rbase = blockIdx.x * 128 + wvu * 32;

#pragma unroll 1
    for (int c = 0; c < 4; ++c) {
        const int r0 = rbase + c * 8;
        if (r0 >= nrows) break;
        float acc[8] = {0.f, 0.f, 0.f, 0.f, 0.f, 0.f, 0.f, 0.f};

        // ---- source 0: XF @ Wi ----
        {
            float w[64];
#pragma unroll
            for (int k = 0; k < 64; ++k) w[k] = Wi[k * 64 + lane];
#pragma unroll
            for (int i = 0; i < 8; ++i) {
                const int r = r0 + i;
                const float* __restrict__ xr =
                    XF + (size_t)(r < nrows ? r : nrows - 1) * 64;
                float a = acc[i];
#pragma unroll
                for (int k = 0; k < 64; ++k) a = fmaf(xr[k], w[k], a);
                acc[i] = a;
            }
        }
        // ---- source 1: XR @ Wo ----
        {
            float w[64];
#pragma unroll
            for (int k = 0; k < 64; ++k) w[k] = Wo[k * 64 + lane];
#pragma unroll
            for (int i = 0; i < 8; ++i) {
                const int r = r0 + i;
                const float* __restrict__ xr =
                    XR + (size_t)(r < nrows ? r : nrows - 1) * 64;
                float a = acc[i];
#pragma unroll
                for (int k = 0; k < 64; ++k) a = fmaf(xr[k], w[k], a);
                acc[i] = a;
            }
        }
        // ---- source 2: XN @ diag(lr) Wl ----
        {
            float w[64];
#pragma unroll
            for (int k = 0; k < 64; ++k) w[k] = Wl[k * 64 + lane] * lr[k];
#pragma unroll
            for (int i = 0; i < 8; ++i) {
                const int r = r0 + i;
                const float* __restrict__ xr =
                    XN + (size_t)(r < nrows ? r : nrows - 1) * 64;
                float a = acc[i];
#pragma unroll
                for (int k = 0; k < 64; ++k) a = fmaf(xr[k], w[k], a);
                acc[i] = a;
            }
        }
#pragma unroll
        for (int i = 0; i < 8; ++i) {
            const int r = r0 + i;
            if (r < nrows)
                C[(size_t)r * 64 + lane] = acc[i] * 0.3333333f + b;
        }
    }
}

// ---------------------------------------------------------------------------
// CSR build
// ---------------------------------------------------------------------------
__global__ __launch_bounds__(256) void k_count(const int* __restrict__ dst,
                                               int* __restrict__ cnt)
{
    const int e = blockIdx.x * 256 + threadIdx.x;
    if (e < NEDGES) atomicAdd(&cnt[dst[e]], 1);
}

__global__ __launch_bounds__(256) void k_scan1(const int* __restrict__ cnt,
                                               int* __restrict__ excl,
                                               int* __restrict__ partials)
{
    __shared__ int s[256];
    const int base = blockIdx.x * SCAN_ELEMS + threadIdx.x * 4;
    int v0 = 0, v1 = 0, v2 = 0, v3 = 0;
    if (base + 0 < NNODES) v0 = cnt[base + 0];
    if (base + 1 < NNODES) v1 = cnt[base + 1];
    if (base + 2 < NNODES) v2 = cnt[base + 2];
    if (base + 3 < NNODES) v3 = cnt[base + 3];
    const int tsum = v0 + v1 + v2 + v3;
    s[threadIdx.x] = tsum;
    __syncthreads();
    for (int off = 1; off < 256; off <<= 1) {
        const int t = (threadIdx.x >= off) ? s[threadIdx.x - off] : 0;
        __syncthreads();
        s[threadIdx.x] += t;
        __syncthreads();
    }
    const int texcl = s[threadIdx.x] - tsum;
    if (base + 0 < NNODES) excl[base + 0] = texcl;
    if (base + 1 < NNODES) excl[base + 1] = texcl + v0;
    if (base + 2 < NNODES) excl[base + 2] = texcl + v0 + v1;
    if (base + 3 < NNODES) excl[base + 3] = texcl + v0 + v1 + v2;
    if (threadIdx.x == 255) partials[blockIdx.x] = s[255];
}

__global__ __launch_bounds__(128) void k_scan2(int* __restrict__ partials, int n)
{
    __shared__ int s[128];
    const int v = (threadIdx.x < n) ? partials[threadIdx.x] : 0;
    s[threadIdx.x] = v;
    __syncthreads();
    for (int off = 1; off < 128; off <<= 1) {
        const int t = (threadIdx.x >= off) ? s[threadIdx.x - off] : 0;
        __syncthreads();
        s[threadIdx.x] += t;
        __syncthreads();
    }
    if (threadIdx.x < n) partials[threadIdx.x] = s[threadIdx.x] - v;
}

__global__ __launch_bounds__(256) void k_addback(const int* __restrict__ excl,
                                                 const int* __restrict__ partials,
                                                 int* __restrict__ rowptr,
                                                 int* __restrict__ cursor)
{
    const int i = blockIdx.x * 256 + threadIdx.x;
    if (i < NNODES) {
        const int v = excl[i] + partials[i >> 10];
        rowptr[i] = v;
        cursor[i] = v;
    }
    if (i == 0) rowptr[NNODES] = NEDGES;
}

__global__ __launch_bounds__(256) void k_scatter(const int* __restrict__ dst,
                                                 const int* __restrict__ src,
                                                 const float* __restrict__ norm,
                                                 const int* __restrict__ is_rev,
                                                 int* __restrict__ cursor,
                                                 int4* __restrict__ meta)
{
    const int e = blockIdx.x * 256 + threadIdx.x;
    if (e >= NEDGES) return;
    const int d = dst[e];
    const int pos = atomicAdd(&cursor[d], 1);
    meta[pos] = make_int4(e, src[e], __float_as_int(norm[e]), is_rev[e]);
}

// ---------------------------------------------------------------------------
// Aggregation: one wave per node. Node index + meta reads are wave-uniform
// (scalar loads); ef/nf gathers are coalesced 256B vector loads.
// ---------------------------------------------------------------------------
__global__ __launch_bounds__(256) void k_agg(
    const float* __restrict__ edge_feat,
    const float* __restrict__ node_feat,
    const int*   __restrict__ rowptr,
    const int4*  __restrict__ meta,
    float* __restrict__ accF,
    float* __restrict__ accR)
{
    const int lane = threadIdx.x & 63;
    const int n    = __builtin_amdgcn_readfirstlane(
                         (int)((blockIdx.x * 256 + threadIdx.x) >> 6));
    if (n >= NNODES) return;

    const int start = rowptr[n];
    const int end   = rowptr[n + 1];
    float af = 0.f, ar = 0.f;
    int j = start;
    for (; j + 3 < end; j += 4) {
        const int4 m0 = meta[j], m1 = meta[j + 1], m2 = meta[j + 2], m3 = meta[j + 3];
        const float e0 = edge_feat[(size_t)m0.x * 64 + lane];
        const float f0 = node_feat[(size_t)m0.y * 64 + lane];
        const float e1 = edge_feat[(size_t)m1.x * 64 + lane];
        const float f1 = node_feat[(size_t)m1.y * 64 + lane];
        const float e2 = edge_feat[(size_t)m2.x * 64 + lane];
        const float f2 = node_feat[(size_t)m2.y * 64 + lane];
        const float e3 = edge_feat[(size_t)m3.x * 64 + lane];
        const float f3 = node_feat[(size_t)m3.y * 64 + lane];
        const float v0 = e0 * f0 * __int_as_float(m0.z);
        const float v1 = e1 * f1 * __int_as_float(m1.z);
        const float v2 = e2 * f2 * __int_as_float(m2.z);
        const float v3 = e3 * f3 * __int_as_float(m3.z);
        af += m0.w ? 0.f : v0;  ar += m0.w ? v0 : 0.f;
        af += m1.w ? 0.f : v1;  ar += m1.w ? v1 : 0.f;
        af += m2.w ? 0.f : v2;  ar += m2.w ? v2 : 0.f;
        af += m3.w ? 0.f : v3;  ar += m3.w ? v3 : 0.f;
    }
    for (; j < end; ++j) {
        const int4 m0 = meta[j];
        const float v0 = edge_feat[(size_t)m0.x * 64 + lane] *
                         node_feat[(size_t)m0.y * 64 + lane] *
                         __int_as_float(m0.z);
        af += m0.w ? 0.f : v0;
        ar += m0.w ? v0 : 0.f;
    }
    accF[(size_t)n * 64 + lane] = af;
    accR[(size_t)n * 64 + lane] = ar;
}

// ---------------------------------------------------------------------------
// Fallback node kernel (LDS version, tolerant of accF==C aliasing; proven).
// ---------------------------------------------------------------------------
__global__ __launch_bounds__(256) void node_gemm_lds(
    const float* XF, const float* XR,
    const float* __restrict__ XN,
    const float* __restrict__ Wi, const float* __restrict__ Wo,
    const float* __restrict__ Wl, const float* __restrict__ loop_rel,
    const float* __restrict__ bias, float* C)
{
    __shared__ float Ws[192][64];
    const int tid = threadIdx.x;
    {
        const float4* wv;
        float4* sv = (float4*)&Ws[0][0];
        wv = (const float4*)Wi;
#pragma unroll
        for (int j = 0; j < 4; ++j) sv[tid + 256 * j] = wv[tid + 256 * j];
        wv = (const float4*)Wo;
#pragma unroll
        for (int j = 0; j < 4; ++j) sv[1024 + tid + 256 * j] = wv[tid + 256 * j];
        wv = (const float4*)Wl;
#pragma unroll
        for (int j = 0; j < 4; ++j) {
            const int f = tid + 256 * j;
            float4 v = wv[f];
            const float s = loop_rel[f >> 4];
            v.x *= s; v.y *= s; v.z *= s; v.w *= s;
            sv[2048 + f] = v;
        }
    }
    __syncthreads();

    const int tx = tid & 15;
    const int ty = tid >> 4;
    const size_t rbase = (size_t)blockIdx.x * 128 + 8 * ty;

    float acc[8][4] = {};
    const float* srcs[3] = { XF, XR, XN };
#pragma unroll
    for (int s = 0; s < 3; ++s) {
        const float* Xs = srcs[s];
#pragma unroll 2
        for (int kc = 0; kc < 16; ++kc) {
            float4 b[4];
#pragma unroll
            for (int kk = 0; kk < 4; ++kk)
                b[kk] = *(const float4*)&Ws[s * 64 + 4 * kc + kk][4 * tx];
#pragma unroll
            for (int i = 0; i < 8; ++i) {
                size_t r = rbase + (size_t)i;
                if (r >= NNODES) r = NNODES - 1;
                const float4 a = ((const float4*)(Xs + r * 64))[kc];
                acc[i][0] += a.x * b[0].x + a.y * b[1].x + a.z * b[2].x + a.w * b[3].x;
                acc[i][1] += a.x * b[0].y + a.y * b[1].y + a.z * b[2].y + a.w * b[3].y;
                acc[i][2] += a.x * b[0].z + a.y * b[1].z + a.z * b[2].z + a.w * b[3].z;
                acc[i][3] += a.x * b[0].w + a.y * b[1].w + a.z * b[2].w + a.w * b[3].w;
            }
        }
    }
    const float4 bb = *(const float4*)(bias + 4 * tx);
    __syncthreads();
#pragma unroll
    for (int i = 0; i < 8; ++i) {
        const size_t r = rbase + (size_t)i;
        if (r < NNODES) {
            float4 o;
            o.x = acc[i][0] * 0.3333333f + bb.x;
            o.y = acc[i][1] * 0.3333333f + bb.y;
            o.z = acc[i][2] * 0.3333333f + bb.z;
            o.w = acc[i][3] * 0.3333333f + bb.w;
            *(float4*)(C + r * 64 + 4 * tx) = o;
        }
    }
}

// ---------------------------------------------------------------------------
// Last-resort fallback scatter.
// ---------------------------------------------------------------------------
__global__ __launch_bounds__(256) void edge_scatter_kernel(
    const float* __restrict__ edge_feat,
    const float* __restrict__ node_feat,
    const float* __restrict__ edge_norm,
    const int*   __restrict__ src,
    const int*   __restrict__ dst,
    const int*   __restrict__ is_rev,
    float* __restrict__ accF,
    float* __restrict__ accR)
{
    const size_t t = (size_t)blockIdx.x * blockDim.x + threadIdx.x;
    if (t >= (size_t)NEDGES * 64) return;
    const int e    = (int)(t >> 6);
    const int lane = (int)(t & 63);
    const float ef   = edge_feat[(size_t)e * 64 + lane];
    const float comp = ef * node_feat[(size_t)src[e] * 64 + lane];
    float* accp = is_rev[e] ? accR : accF;
    unsafeAtomicAdd(accp + (size_t)dst[e] * 64 + lane, comp * edge_norm[e]);
}

// ---------------------------------------------------------------------------
extern "C" void kernel_launch(void* const* d_in, const int* in_sizes, int n_in,
                              void* d_out, int out_size, void* d_ws, size_t ws_size,
                              hipStream_t stream)
{
    const float* node_feat = (const float*)d_in[0];
    const float* edge_feat = (const float*)d_in[1];
    const float* edge_norm = (const float*)d_in[2];
    const int*   src       = (const int*)d_in[3];
    const int*   dst       = (const int*)d_in[4];
    const int*   is_rev    = (const int*)d_in[5];
    const float* in_w      = (const float*)d_in[6];
    const float* out_w     = (const float*)d_in[7];
    const float* rel_w     = (const float*)d_in[8];
    const float* loop_w    = (const float*)d_in[9];
    const float* loop_rel  = (const float*)d_in[10];
    const float* bias      = (const float*)d_in[11];

    float* node_out = (float*)d_out;
    float* edge_out = (float*)d_out + (size_t)NNODES * 64;

    const size_t accBytes = (size_t)NNODES * 64 * sizeof(float);
    const int edgeThreadBlocks = (NEDGES + 255) / 256;
    const int rowGemmEdgeBlocks = (NEDGES + 127) / 128;      // 10000
    const int rowGemmNodeBlocks = (NNODES + 127) / 128;      // 782
    const int aggBlocks         = (NNODES + 3) / 4;          // 25000

    // ws layout
    char* p = (char*)d_ws;
    int* cnt      = (int*)p;                 p += (size_t)NNODES * 4;
    int* excl     = (int*)p;                 p += (size_t)NNODES * 4;
    int* partials = (int*)p;                 p += 128 * 4;
    int* rowptr   = (int*)p;                 p += (size_t)(NNODES + 1) * 4;
    int* cursor   = (int*)p;                 p += (size_t)NNODES * 4;
    p = (char*)(((uintptr_t)p + 15) & ~(uintptr_t)15);
    int4* meta    = (int4*)p;                p += (size_t)NEDGES * 16;
    const size_t needed1 = (size_t)(p - (char*)d_ws);
    float* wsF    = (float*)p;               p += accBytes;
    float* wsR    = (float*)p;               p += accBytes;
    const size_t needed2 = (size_t)(p - (char*)d_ws);

    if (ws_size >= needed1) {
        const bool bigws = (ws_size >= needed2);
        // accumulators: workspace if it fits (non-aliased scalar node kernel),
        // else borrow d_out regions (aliasing-tolerant LDS node kernel).
        float* accF = bigws ? wsF : node_out;
        float* accR = bigws ? wsR : edge_out;

        hipMemsetAsync(cnt, 0, (size_t)NNODES * 4, stream);
        k_count<<<edgeThreadBlocks, 256, 0, stream>>>(dst, cnt);
        k_scan1<<<NSCAN, 256, 0, stream>>>(cnt, excl, partials);
        k_scan2<<<1, 128, 0, stream>>>(partials, NSCAN);
        k_addback<<<(NNODES + 255) / 256, 256, 0, stream>>>(excl, partials, rowptr, cursor);
        k_scatter<<<edgeThreadBlocks, 256, 0, stream>>>(dst, src, edge_norm, is_rev, cursor, meta);
        k_agg<<<aggBlocks, 256, 0, stream>>>(edge_feat, node_feat, rowptr, meta, accF, accR);
        if (bigws) {
            node_gemm3<<<rowGemmNodeBlocks, 256, 0, stream>>>(
                accF, accR, node_feat, in_w, out_w, loop_w, loop_rel, bias,
                node_out, NNODES);
        } else {
            node_gemm_lds<<<rowGemmNodeBlocks, 256, 0, stream>>>(
                accF, accR, node_feat, in_w, out_w, loop_w, loop_rel, bias, node_out);
        }
        gemm64_rows<<<rowGemmEdgeBlocks, 256, 0, stream>>>(
            edge_feat, rel_w, edge_out, NEDGES);
    } else {
        // Atomic fallback with d_out borrowing.
        float* accF = node_out;
        float* accR = edge_out;
        hipMemsetAsync(d_out, 0, 2 * accBytes, stream);
        edge_scatter_kernel<<<(int)(((size_t)NEDGES * 64 + 255) / 256), 256, 0, stream>>>(
            edge_feat, node_feat, edge_norm, src, dst, is_rev, accF, accR);
        node_gemm_lds<<<rowGemmNodeBlocks, 256, 0, stream>>>(
            accF, accR, node_feat, in_w, out_w, loop_w, loop_rel, bias, node_out);
        gemm64_rows<<<rowGemmEdgeBlocks, 256, 0, stream>>>(
            edge_feat, rel_w, edge_out, NEDGES);
    }
}

// Round 5
// 491.833 us; speedup vs baseline: 2.9003x; 2.9003x over previous
//
#include <hip/hip_runtime.h>

constexpr int NNODES = 100000;
constexpr int NEDGES = 1280000;
constexpr int SCAN_ELEMS = 1024;
constexpr int NSCAN = (NNODES + SCAN_ELEMS - 1) / SCAN_ELEMS;  // 98

typedef __attribute__((ext_vector_type(8))) short bf16x8;
typedef __attribute__((ext_vector_type(4))) float f32x4;

__device__ inline unsigned short f2bf(float x) {
    unsigned u = __float_as_uint(x);
    u += 0x7FFFu + ((u >> 16) & 1u);     // round-to-nearest-even
    return (unsigned short)(u >> 16);
}

// ---------------------------------------------------------------------------
// W prep: WT[n][k] = bf16(W[k][n]), 64x64.
// ---------------------------------------------------------------------------
__global__ __launch_bounds__(256) void k_wprep(const float* __restrict__ W,
                                               unsigned short* __restrict__ WT)
{
    const int t = blockIdx.x * 256 + threadIdx.x;
    if (t < 4096) {
        const int k = t >> 6, n = t & 63;
        WT[n * 64 + k] = f2bf(W[k * 64 + n]);
    }
}

// ---------------------------------------------------------------------------
// MFMA edge GEMM: C[E,64] = X[E,64] @ W[64,64], X f32 -> bf16 in-reg.
// Block = 4 waves x 64 rows = 256 rows. Zero LDS. A-frags loaded dense from
// global (8 consecutive k per lane); B-frags 16B loads from bf16 WT (L1-hot).
// mfma_f32_16x16x32_bf16: A row=l&15,k=(l>>4)*8+j; B col=l&15, same k;
// C col=l&15, row=(l>>4)*4+reg  [m89/m92 verified layouts].
// ---------------------------------------------------------------------------
__global__ __launch_bounds__(256) void mfma_edge_gemm(
    const float* __restrict__ X,
    const unsigned short* __restrict__ WT,   // [64 n][64 k] bf16
    float* __restrict__ C)
{
    const int lane = threadIdx.x & 63;
    const int wv   = threadIdx.x >> 6;
    const int R0   = blockIdx.x * 256 + wv * 64;
    const int lr   = lane & 15;          // A row / B col / C col
    const int lk8  = (lane >> 4) * 8;    // k-run start
    const int crow = (lane >> 4) * 4;    // C row base

    // B fragments (4 col-tiles x 2 k-steps), 16B each from bf16 WT.
    bf16x8 fb[4][2];
#pragma unroll
    for (int nt = 0; nt < 4; ++nt)
#pragma unroll
        for (int ks = 0; ks < 2; ++ks)
            fb[nt][ks] = *(const bf16x8*)(WT + (size_t)(nt * 16 + lr) * 64 + ks * 32 + lk8);

    // A fragments (4 row-tiles x 2 k-steps): two float4 loads + cvt each.
    bf16x8 fa[4][2];
#pragma unroll
    for (int rt = 0; rt < 4; ++rt) {
        const float* xp = X + (size_t)(R0 + rt * 16 + lr) * 64 + lk8;
#pragma unroll
        for (int ks = 0; ks < 2; ++ks) {
            const float4 a0 = *(const float4*)(xp + ks * 32);
            const float4 a1 = *(const float4*)(xp + ks * 32 + 4);
            bf16x8 f;
            f[0] = (short)f2bf(a0.x); f[1] = (short)f2bf(a0.y);
            f[2] = (short)f2bf(a0.z); f[3] = (short)f2bf(a0.w);
            f[4] = (short)f2bf(a1.x); f[5] = (short)f2bf(a1.y);
            f[6] = (short)f2bf(a1.z); f[7] = (short)f2bf(a1.w);
            fa[rt][ks] = f;
        }
    }

#pragma unroll
    for (int rt = 0; rt < 4; ++rt) {
#pragma unroll
        for (int nt = 0; nt < 4; ++nt) {
            f32x4 acc = {0.f, 0.f, 0.f, 0.f};
            acc = __builtin_amdgcn_mfma_f32_16x16x32_bf16(fa[rt][0], fb[nt][0], acc, 0, 0, 0);
            acc = __builtin_amdgcn_mfma_f32_16x16x32_bf16(fa[rt][1], fb[nt][1], acc, 0, 0, 0);
            float* cp = C + (size_t)(R0 + rt * 16 + crow) * 64 + nt * 16 + lr;
            cp[0]   = acc[0];
            cp[64]  = acc[1];
            cp[128] = acc[2];
            cp[192] = acc[3];
        }
    }
}

// ---------------------------------------------------------------------------
// Fallback f32 edge GEMM (R3-proven).
// ---------------------------------------------------------------------------
__global__ __launch_bounds__(256) void edge_gemm_f32(
    const float* __restrict__ X,
    const float* __restrict__ W,
    float* __restrict__ C)
{
    __shared__ float Ws[64][64];
    const int tid = threadIdx.x;
    {
        const float4* Wv = (const float4*)W;
        float4* Sv = (float4*)&Ws[0][0];
#pragma unroll
        for (int j = 0; j < 4; ++j) Sv[tid + 256 * j] = Wv[tid + 256 * j];
    }
    __syncthreads();

    const int tx = tid & 15;
    const int ty = tid >> 4;
    const size_t rbase = (size_t)blockIdx.x * 128 + 8 * ty;
    const float* Xp = X + rbase * 64;

    float acc[8][4] = {};
#pragma unroll 2
    for (int kc = 0; kc < 16; ++kc) {
        float4 b[4];
#pragma unroll
        for (int kk = 0; kk < 4; ++kk)
            b[kk] = *(const float4*)&Ws[4 * kc + kk][4 * tx];
#pragma unroll
        for (int i = 0; i < 8; ++i) {
            const float4 a = ((const float4*)(Xp + (size_t)i * 64))[kc];
            acc[i][0] += a.x * b[0].x + a.y * b[1].x + a.z * b[2].x + a.w * b[3].x;
            acc[i][1] += a.x * b[0].y + a.y * b[1].y + a.z * b[2].y + a.w * b[3].y;
            acc[i][2] += a.x * b[0].z + a.y * b[1].z + a.z * b[2].z + a.w * b[3].z;
            acc[i][3] += a.x * b[0].w + a.y * b[1].w + a.z * b[2].w + a.w * b[3].w;
        }
    }
#pragma unroll
    for (int i = 0; i < 8; ++i) {
        float4 o = make_float4(acc[i][0], acc[i][1], acc[i][2], acc[i][3]);
        *(float4*)(C + (rbase + (size_t)i) * 64 + 4 * tx) = o;
    }
}

// ---------------------------------------------------------------------------
// CSR build
// ---------------------------------------------------------------------------
__global__ __launch_bounds__(256) void k_count(const int* __restrict__ dst,
                                               int* __restrict__ cnt)
{
    const int e = blockIdx.x * 256 + threadIdx.x;
    if (e < NEDGES) atomicAdd(&cnt[dst[e]], 1);
}

__global__ __launch_bounds__(256) void k_scan1(const int* __restrict__ cnt,
                                               int* __restrict__ excl,
                                               int* __restrict__ partials)
{
    __shared__ int s[256];
    const int base = blockIdx.x * SCAN_ELEMS + threadIdx.x * 4;
    int v0 = 0, v1 = 0, v2 = 0, v3 = 0;
    if (base + 0 < NNODES) v0 = cnt[base + 0];
    if (base + 1 < NNODES) v1 = cnt[base + 1];
    if (base + 2 < NNODES) v2 = cnt[base + 2];
    if (base + 3 < NNODES) v3 = cnt[base + 3];
    const int tsum = v0 + v1 + v2 + v3;
    s[threadIdx.x] = tsum;
    __syncthreads();
    for (int off = 1; off < 256; off <<= 1) {
        const int t = (threadIdx.x >= off) ? s[threadIdx.x - off] : 0;
        __syncthreads();
        s[threadIdx.x] += t;
        __syncthreads();
    }
    const int texcl = s[threadIdx.x] - tsum;
    if (base + 0 < NNODES) excl[base + 0] = texcl;
    if (base + 1 < NNODES) excl[base + 1] = texcl + v0;
    if (base + 2 < NNODES) excl[base + 2] = texcl + v0 + v1;
    if (base + 3 < NNODES) excl[base + 3] = texcl + v0 + v1 + v2;
    if (threadIdx.x == 255) partials[blockIdx.x] = s[255];
}

__global__ __launch_bounds__(128) void k_scan2(int* __restrict__ partials, int n)
{
    __shared__ int s[128];
    const int v = (threadIdx.x < n) ? partials[threadIdx.x] : 0;
    s[threadIdx.x] = v;
    __syncthreads();
    for (int off = 1; off < 128; off <<= 1) {
        const int t = (threadIdx.x >= off) ? s[threadIdx.x - off] : 0;
        __syncthreads();
        s[threadIdx.x] += t;
        __syncthreads();
    }
    if (threadIdx.x < n) partials[threadIdx.x] = s[threadIdx.x] - v;
}

__global__ __launch_bounds__(256) void k_addback(const int* __restrict__ excl,
                                                 const int* __restrict__ partials,
                                                 int* __restrict__ rowptr,
                                                 int* __restrict__ cursor)
{
    const int i = blockIdx.x * 256 + threadIdx.x;
    if (i < NNODES) {
        const int v = excl[i] + partials[i >> 10];
        rowptr[i] = v;
        cursor[i] = v;
    }
    if (i == 0) rowptr[NNODES] = NEDGES;
}

__global__ __launch_bounds__(256) void k_scatter(const int* __restrict__ dst,
                                                 const int* __restrict__ src,
                                                 const float* __restrict__ norm,
                                                 const int* __restrict__ is_rev,
                                                 int* __restrict__ cursor,
                                                 int4* __restrict__ meta)
{
    const int e = blockIdx.x * 256 + threadIdx.x;
    if (e >= NEDGES) return;
    const int d = dst[e];
    const int pos = atomicAdd(&cursor[d], 1);
    meta[pos] = make_int4(e, src[e], __float_as_int(norm[e]), is_rev[e]);
}

// ---------------------------------------------------------------------------
// Aggregation: one wave per node, unroll-4 gather, no atomics (R3-proven).
// ---------------------------------------------------------------------------
__global__ __launch_bounds__(256) void k_agg(
    const float* __restrict__ edge_feat,
    const float* __restrict__ node_feat,
    const int*   __restrict__ rowptr,
    const int4*  __restrict__ meta,
    float* __restrict__ accF,
    float* __restrict__ accR)
{
    const int lane = threadIdx.x & 63;
    const int n    = (blockIdx.x * blockDim.x + threadIdx.x) >> 6;
    if (n >= NNODES) return;

    const int start = rowptr[n];
    const int end   = rowptr[n + 1];
    float af = 0.f, ar = 0.f;
    int j = start;
    for (; j + 3 < end; j += 4) {
        const int4 m0 = meta[j], m1 = meta[j + 1], m2 = meta[j + 2], m3 = meta[j + 3];
        const float e0 = edge_feat[(size_t)m0.x * 64 + lane];
        const float f0 = node_feat[(size_t)m0.y * 64 + lane];
        const float e1 = edge_feat[(size_t)m1.x * 64 + lane];
        const float f1 = node_feat[(size_t)m1.y * 64 + lane];
        const float e2 = edge_feat[(size_t)m2.x * 64 + lane];
        const float f2 = node_feat[(size_t)m2.y * 64 + lane];
        const float e3 = edge_feat[(size_t)m3.x * 64 + lane];
        const float f3 = node_feat[(size_t)m3.y * 64 + lane];
        const float v0 = e0 * f0 * __int_as_float(m0.z);
        const float v1 = e1 * f1 * __int_as_float(m1.z);
        const float v2 = e2 * f2 * __int_as_float(m2.z);
        const float v3 = e3 * f3 * __int_as_float(m3.z);
        af += m0.w ? 0.f : v0;  ar += m0.w ? v0 : 0.f;
        af += m1.w ? 0.f : v1;  ar += m1.w ? v1 : 0.f;
        af += m2.w ? 0.f : v2;  ar += m2.w ? v2 : 0.f;
        af += m3.w ? 0.f : v3;  ar += m3.w ? v3 : 0.f;
    }
    for (; j < end; ++j) {
        const int4 m0 = meta[j];
        const float v0 = edge_feat[(size_t)m0.x * 64 + lane] *
                         node_feat[(size_t)m0.y * 64 + lane] *
                         __int_as_float(m0.z);
        af += m0.w ? 0.f : v0;
        ar += m0.w ? v0 : 0.f;
    }
    accF[(size_t)n * 64 + lane] = af;
    accR[(size_t)n * 64 + lane] = ar;
}

// ---------------------------------------------------------------------------
// Node kernel (R3-proven; aliasing-tolerant: reads -> barrier -> stores).
// ---------------------------------------------------------------------------
__global__ __launch_bounds__(256) void node_gemm_lds(
    const float* XF, const float* XR,
    const float* __restrict__ XN,
    const float* __restrict__ Wi, const float* __restrict__ Wo,
    const float* __restrict__ Wl, const float* __restrict__ loop_rel,
    const float* __restrict__ bias, float* C)
{
    __shared__ float Ws[192][64];
    const int tid = threadIdx.x;
    {
        const float4* wv;
        float4* sv = (float4*)&Ws[0][0];
        wv = (const float4*)Wi;
#pragma unroll
        for (int j = 0; j < 4; ++j) sv[tid + 256 * j] = wv[tid + 256 * j];
        wv = (const float4*)Wo;
#pragma unroll
        for (int j = 0; j < 4; ++j) sv[1024 + tid + 256 * j] = wv[tid + 256 * j];
        wv = (const float4*)Wl;
#pragma unroll
        for (int j = 0; j < 4; ++j) {
            const int f = tid + 256 * j;
            float4 v = wv[f];
            const float s = loop_rel[f >> 4];
            v.x *= s; v.y *= s; v.z *= s; v.w *= s;
            sv[2048 + f] = v;
        }
    }
    __syncthreads();

    const int tx = tid & 15;
    const int ty = tid >> 4;
    const size_t rbase = (size_t)blockIdx.x * 128 + 8 * ty;

    float acc[8][4] = {};
    const float* srcs[3] = { XF, XR, XN };
#pragma unroll
    for (int s = 0; s < 3; ++s) {
        const float* Xs = srcs[s];
#pragma unroll 2
        for (int kc = 0; kc < 16; ++kc) {
            float4 b[4];
#pragma unroll
            for (int kk = 0; kk < 4; ++kk)
                b[kk] = *(const float4*)&Ws[s * 64 + 4 * kc + kk][4 * tx];
#pragma unroll
            for (int i = 0; i < 8; ++i) {
                size_t r = rbase + (size_t)i;
                if (r >= NNODES) r = NNODES - 1;
                const float4 a = ((const float4*)(Xs + r * 64))[kc];
                acc[i][0] += a.x * b[0].x + a.y * b[1].x + a.z * b[2].x + a.w * b[3].x;
                acc[i][1] += a.x * b[0].y + a.y * b[1].y + a.z * b[2].y + a.w * b[3].y;
                acc[i][2] += a.x * b[0].z + a.y * b[1].z + a.z * b[2].z + a.w * b[3].z;
                acc[i][3] += a.x * b[0].w + a.y * b[1].w + a.z * b[2].w + a.w * b[3].w;
            }
        }
    }
    const float4 bb = *(const float4*)(bias + 4 * tx);
    __syncthreads();
#pragma unroll
    for (int i = 0; i < 8; ++i) {
        const size_t r = rbase + (size_t)i;
        if (r < NNODES) {
            float4 o;
            o.x = acc[i][0] * 0.3333333f + bb.x;
            o.y = acc[i][1] * 0.3333333f + bb.y;
            o.z = acc[i][2] * 0.3333333f + bb.z;
            o.w = acc[i][3] * 0.3333333f + bb.w;
            *(float4*)(C + r * 64 + 4 * tx) = o;
        }
    }
}

// ---------------------------------------------------------------------------
// Last-resort fallback scatter.
// ---------------------------------------------------------------------------
__global__ __launch_bounds__(256) void edge_scatter_kernel(
    const float* __restrict__ edge_feat,
    const float* __restrict__ node_feat,
    const float* __restrict__ edge_norm,
    const int*   __restrict__ src,
    const int*   __restrict__ dst,
    const int*   __restrict__ is_rev,
    float* __restrict__ accF,
    float* __restrict__ accR)
{
    const size_t t = (size_t)blockIdx.x * blockDim.x + threadIdx.x;
    if (t >= (size_t)NEDGES * 64) return;
    const int e    = (int)(t >> 6);
    const int lane = (int)(t & 63);
    const float ef   = edge_feat[(size_t)e * 64 + lane];
    const float comp = ef * node_feat[(size_t)src[e] * 64 + lane];
    float* accp = is_rev[e] ? accR : accF;
    unsafeAtomicAdd(accp + (size_t)dst[e] * 64 + lane, comp * edge_norm[e]);
}

// ---------------------------------------------------------------------------
extern "C" void kernel_launch(void* const* d_in, const int* in_sizes, int n_in,
                              void* d_out, int out_size, void* d_ws, size_t ws_size,
                              hipStream_t stream)
{
    const float* node_feat = (const float*)d_in[0];
    const float* edge_feat = (const float*)d_in[1];
    const float* edge_norm = (const float*)d_in[2];
    const int*   src       = (const int*)d_in[3];
    const int*   dst       = (const int*)d_in[4];
    const int*   is_rev    = (const int*)d_in[5];
    const float* in_w      = (const float*)d_in[6];
    const float* out_w     = (const float*)d_in[7];
    const float* rel_w     = (const float*)d_in[8];
    const float* loop_w    = (const float*)d_in[9];
    const float* loop_rel  = (const float*)d_in[10];
    const float* bias      = (const float*)d_in[11];

    float* node_out = (float*)d_out;
    float* edge_out = (float*)d_out + (size_t)NNODES * 64;

    const size_t accBytes = (size_t)NNODES * 64 * sizeof(float);
    const int edgeThreadBlocks = (NEDGES + 255) / 256;
    const int mfmaEdgeBlocks   = NEDGES / 256;               // 5000 (exact)
    const int f32EdgeBlocks    = (NEDGES + 127) / 128;       // 10000
    const int nodeGemmBlocks   = (NNODES + 127) / 128;       // 782
    const int aggBlocks        = (NNODES + 3) / 4;           // 25000

    // ws layout
    char* p = (char*)d_ws;
    unsigned short* wtb = (unsigned short*)p;  p += 64 * 64 * 2;   // 8 KB bf16 W^T
    int* cnt      = (int*)p;                 p += (size_t)NNODES * 4;
    int* excl     = (int*)p;                 p += (size_t)NNODES * 4;
    int* partials = (int*)p;                 p += 128 * 4;
    int* rowptr   = (int*)p;                 p += (size_t)(NNODES + 1) * 4;
    int* cursor   = (int*)p;                 p += (size_t)NNODES * 4;
    p = (char*)(((uintptr_t)p + 15) & ~(uintptr_t)15);
    int4* meta    = (int4*)p;                p += (size_t)NEDGES * 16;
    const size_t needed = (size_t)(p - (char*)d_ws);

    // accF borrows node_out (node_gemm_lds in-place safe);
    // accR borrows edge_out (overwritten afterwards by the edge GEMM).
    float* accF = node_out;
    float* accR = edge_out;

    if (ws_size >= needed) {
        hipMemsetAsync(cnt, 0, (size_t)NNODES * 4, stream);
        k_wprep<<<16, 256, 0, stream>>>(rel_w, wtb);
        k_count<<<edgeThreadBlocks, 256, 0, stream>>>(dst, cnt);
        k_scan1<<<NSCAN, 256, 0, stream>>>(cnt, excl, partials);
        k_scan2<<<1, 128, 0, stream>>>(partials, NSCAN);
        k_addback<<<(NNODES + 255) / 256, 256, 0, stream>>>(excl, partials, rowptr, cursor);
        k_scatter<<<edgeThreadBlocks, 256, 0, stream>>>(dst, src, edge_norm, is_rev, cursor, meta);
        k_agg<<<aggBlocks, 256, 0, stream>>>(edge_feat, node_feat, rowptr, meta, accF, accR);
        node_gemm_lds<<<nodeGemmBlocks, 256, 0, stream>>>(
            accF, accR, node_feat, in_w, out_w, loop_w, loop_rel, bias, node_out);
        mfma_edge_gemm<<<mfmaEdgeBlocks, 256, 0, stream>>>(edge_feat, wtb, edge_out);
    } else {
        // Atomic fallback with d_out borrowing (all-f32).
        hipMemsetAsync(d_out, 0, 2 * accBytes, stream);
        edge_scatter_kernel<<<(int)(((size_t)NEDGES * 64 + 255) / 256), 256, 0, stream>>>(
            edge_feat, node_feat, edge_norm, src, dst, is_rev, accF, accR);
        node_gemm_lds<<<nodeGemmBlocks, 256, 0, stream>>>(
            accF, accR, node_feat, in_w, out_w, loop_w, loop_rel, bias, node_out);
        edge_gemm_f32<<<f32EdgeBlocks, 256, 0, stream>>>(edge_feat, rel_w, edge_out);
    }
}

// Round 6
// 490.748 us; speedup vs baseline: 2.9067x; 1.0022x over previous
//
#include <hip/hip_runtime.h>

constexpr int NNODES = 100000;
constexpr int NEDGES = 1280000;
constexpr int SCAN_ELEMS = 1024;
constexpr int NSCAN = (NNODES + SCAN_ELEMS - 1) / SCAN_ELEMS;  // 98

typedef __attribute__((ext_vector_type(8))) short bf16x8;
typedef __attribute__((ext_vector_type(4))) float f32x4;

__device__ inline unsigned short f2bf(float x) {
    unsigned u = __float_as_uint(x);
    u += 0x7FFFu + ((u >> 16) & 1u);     // round-to-nearest-even
    return (unsigned short)(u >> 16);
}

// ---------------------------------------------------------------------------
// Zero the count array ourselves: hipMemsetAsync's fillBufferAligned ran at
// 2 GB/s / 209us for this 400KB buffer (tiny-grid fill kernel). 98x256 int4
// stores ~3us.
// ---------------------------------------------------------------------------
__global__ __launch_bounds__(256) void k_zero(int4* __restrict__ p, int n4)
{
    const int i = blockIdx.x * 256 + threadIdx.x;
    if (i < n4) p[i] = make_int4(0, 0, 0, 0);
}

// ---------------------------------------------------------------------------
// W prep: WT[n][k] = bf16(W[k][n]), 64x64.
// ---------------------------------------------------------------------------
__global__ __launch_bounds__(256) void k_wprep(const float* __restrict__ W,
                                               unsigned short* __restrict__ WT)
{
    const int t = blockIdx.x * 256 + threadIdx.x;
    if (t < 4096) {
        const int k = t >> 6, n = t & 63;
        WT[n * 64 + k] = f2bf(W[k * 64 + n]);
    }
}

// ---------------------------------------------------------------------------
// MFMA edge GEMM: C[E,64] = X[E,64] @ W[64,64], X f32 -> bf16 in-reg.
// Block = 4 waves x 64 rows = 256 rows. Zero LDS. A-frags loaded dense from
// global; B-frags 16B loads from bf16 WT (L1-hot).
// ---------------------------------------------------------------------------
__global__ __launch_bounds__(256) void mfma_edge_gemm(
    const float* __restrict__ X,
    const unsigned short* __restrict__ WT,   // [64 n][64 k] bf16
    float* __restrict__ C)
{
    const int lane = threadIdx.x & 63;
    const int wv   = threadIdx.x >> 6;
    const int R0   = blockIdx.x * 256 + wv * 64;
    const int lr   = lane & 15;          // A row / B col / C col
    const int lk8  = (lane >> 4) * 8;    // k-run start
    const int crow = (lane >> 4) * 4;    // C row base

    bf16x8 fb[4][2];
#pragma unroll
    for (int nt = 0; nt < 4; ++nt)
#pragma unroll
        for (int ks = 0; ks < 2; ++ks)
            fb[nt][ks] = *(const bf16x8*)(WT + (size_t)(nt * 16 + lr) * 64 + ks * 32 + lk8);

    bf16x8 fa[4][2];
#pragma unroll
    for (int rt = 0; rt < 4; ++rt) {
        const float* xp = X + (size_t)(R0 + rt * 16 + lr) * 64 + lk8;
#pragma unroll
        for (int ks = 0; ks < 2; ++ks) {
            const float4 a0 = *(const float4*)(xp + ks * 32);
            const float4 a1 = *(const float4*)(xp + ks * 32 + 4);
            bf16x8 f;
            f[0] = (short)f2bf(a0.x); f[1] = (short)f2bf(a0.y);
            f[2] = (short)f2bf(a0.z); f[3] = (short)f2bf(a0.w);
            f[4] = (short)f2bf(a1.x); f[5] = (short)f2bf(a1.y);
            f[6] = (short)f2bf(a1.z); f[7] = (short)f2bf(a1.w);
            fa[rt][ks] = f;
        }
    }

#pragma unroll
    for (int rt = 0; rt < 4; ++rt) {
#pragma unroll
        for (int nt = 0; nt < 4; ++nt) {
            f32x4 acc = {0.f, 0.f, 0.f, 0.f};
            acc = __builtin_amdgcn_mfma_f32_16x16x32_bf16(fa[rt][0], fb[nt][0], acc, 0, 0, 0);
            acc = __builtin_amdgcn_mfma_f32_16x16x32_bf16(fa[rt][1], fb[nt][1], acc, 0, 0, 0);
            float* cp = C + (size_t)(R0 + rt * 16 + crow) * 64 + nt * 16 + lr;
            cp[0]   = acc[0];
            cp[64]  = acc[1];
            cp[128] = acc[2];
            cp[192] = acc[3];
        }
    }
}

// ---------------------------------------------------------------------------
// Fallback f32 edge GEMM (R3-proven).
// ---------------------------------------------------------------------------
__global__ __launch_bounds__(256) void edge_gemm_f32(
    const float* __restrict__ X,
    const float* __restrict__ W,
    float* __restrict__ C)
{
    __shared__ float Ws[64][64];
    const int tid = threadIdx.x;
    {
        const float4* Wv = (const float4*)W;
        float4* Sv = (float4*)&Ws[0][0];
#pragma unroll
        for (int j = 0; j < 4; ++j) Sv[tid + 256 * j] = Wv[tid + 256 * j];
    }
    __syncthreads();

    const int tx = tid & 15;
    const int ty = tid >> 4;
    const size_t rbase = (size_t)blockIdx.x * 128 + 8 * ty;
    const float* Xp = X + rbase * 64;

    float acc[8][4] = {};
#pragma unroll 2
    for (int kc = 0; kc < 16; ++kc) {
        float4 b[4];
#pragma unroll
        for (int kk = 0; kk < 4; ++kk)
            b[kk] = *(const float4*)&Ws[4 * kc + kk][4 * tx];
#pragma unroll
        for (int i = 0; i < 8; ++i) {
            const float4 a = ((const float4*)(Xp + (size_t)i * 64))[kc];
            acc[i][0] += a.x * b[0].x + a.y * b[1].x + a.z * b[2].x + a.w * b[3].x;
            acc[i][1] += a.x * b[0].y + a.y * b[1].y + a.z * b[2].y + a.w * b[3].y;
            acc[i][2] += a.x * b[0].z + a.y * b[1].z + a.z * b[2].z + a.w * b[3].z;
            acc[i][3] += a.x * b[0].w + a.y * b[1].w + a.z * b[2].w + a.w * b[3].w;
        }
    }
#pragma unroll
    for (int i = 0; i < 8; ++i) {
        float4 o = make_float4(acc[i][0], acc[i][1], acc[i][2], acc[i][3]);
        *(float4*)(C + (rbase + (size_t)i) * 64 + 4 * tx) = o;
    }
}

// ---------------------------------------------------------------------------
// CSR build
// ---------------------------------------------------------------------------
__global__ __launch_bounds__(256) void k_count(const int* __restrict__ dst,
                                               int* __restrict__ cnt)
{
    const int e = blockIdx.x * 256 + threadIdx.x;
    if (e < NEDGES) atomicAdd(&cnt[dst[e]], 1);
}

__global__ __launch_bounds__(256) void k_scan1(const int* __restrict__ cnt,
                                               int* __restrict__ excl,
                                               int* __restrict__ partials)
{
    __shared__ int s[256];
    const int base = blockIdx.x * SCAN_ELEMS + threadIdx.x * 4;
    int v0 = 0, v1 = 0, v2 = 0, v3 = 0;
    if (base + 0 < NNODES) v0 = cnt[base + 0];
    if (base + 1 < NNODES) v1 = cnt[base + 1];
    if (base + 2 < NNODES) v2 = cnt[base + 2];
    if (base + 3 < NNODES) v3 = cnt[base + 3];
    const int tsum = v0 + v1 + v2 + v3;
    s[threadIdx.x] = tsum;
    __syncthreads();
    for (int off = 1; off < 256; off <<= 1) {
        const int t = (threadIdx.x >= off) ? s[threadIdx.x - off] : 0;
        __syncthreads();
        s[threadIdx.x] += t;
        __syncthreads();
    }
    const int texcl = s[threadIdx.x] - tsum;
    if (base + 0 < NNODES) excl[base + 0] = texcl;
    if (base + 1 < NNODES) excl[base + 1] = texcl + v0;
    if (base + 2 < NNODES) excl[base + 2] = texcl + v0 + v1;
    if (base + 3 < NNODES) excl[base + 3] = texcl + v0 + v1 + v2;
    if (threadIdx.x == 255) partials[blockIdx.x] = s[255];
}

__global__ __launch_bounds__(128) void k_scan2(int* __restrict__ partials, int n)
{
    __shared__ int s[128];
    const int v = (threadIdx.x < n) ? partials[threadIdx.x] : 0;
    s[threadIdx.x] = v;
    __syncthreads();
    for (int off = 1; off < 128; off <<= 1) {
        const int t = (threadIdx.x >= off) ? s[threadIdx.x - off] : 0;
        __syncthreads();
        s[threadIdx.x] += t;
        __syncthreads();
    }
    if (threadIdx.x < n) partials[threadIdx.x] = s[threadIdx.x] - v;
}

__global__ __launch_bounds__(256) void k_addback(const int* __restrict__ excl,
                                                 const int* __restrict__ partials,
                                                 int* __restrict__ rowptr,
                                                 int* __restrict__ cursor)
{
    const int i = blockIdx.x * 256 + threadIdx.x;
    if (i < NNODES) {
        const int v = excl[i] + partials[i >> 10];
        rowptr[i] = v;
        cursor[i] = v;
    }
    if (i == 0) rowptr[NNODES] = NEDGES;
}

__global__ __launch_bounds__(256) void k_scatter(const int* __restrict__ dst,
                                                 const int* __restrict__ src,
                                                 const float* __restrict__ norm,
                                                 const int* __restrict__ is_rev,
                                                 int* __restrict__ cursor,
                                                 int4* __restrict__ meta)
{
    const int e = blockIdx.x * 256 + threadIdx.x;
    if (e >= NEDGES) return;
    const int d = dst[e];
    const int pos = atomicAdd(&cursor[d], 1);
    meta[pos] = make_int4(e, src[e], __float_as_int(norm[e]), is_rev[e]);
}

// ---------------------------------------------------------------------------
// Aggregation: one wave per node, unroll-4 gather, no atomics (R3-proven).
// ---------------------------------------------------------------------------
__global__ __launch_bounds__(256) void k_agg(
    const float* __restrict__ edge_feat,
    const float* __restrict__ node_feat,
    const int*   __restrict__ rowptr,
    const int4*  __restrict__ meta,
    float* __restrict__ accF,
    float* __restrict__ accR)
{
    const int lane = threadIdx.x & 63;
    const int n    = (blockIdx.x * blockDim.x + threadIdx.x) >> 6;
    if (n >= NNODES) return;

    const int start = rowptr[n];
    const int end   = rowptr[n + 1];
    float af = 0.f, ar = 0.f;
    int j = start;
    for (; j + 3 < end; j += 4) {
        const int4 m0 = meta[j], m1 = meta[j + 1], m2 = meta[j + 2], m3 = meta[j + 3];
        const float e0 = edge_feat[(size_t)m0.x * 64 + lane];
        const float f0 = node_feat[(size_t)m0.y * 64 + lane];
        const float e1 = edge_feat[(size_t)m1.x * 64 + lane];
        const float f1 = node_feat[(size_t)m1.y * 64 + lane];
        const float e2 = edge_feat[(size_t)m2.x * 64 + lane];
        const float f2 = node_feat[(size_t)m2.y * 64 + lane];
        const float e3 = edge_feat[(size_t)m3.x * 64 + lane];
        const float f3 = node_feat[(size_t)m3.y * 64 + lane];
        const float v0 = e0 * f0 * __int_as_float(m0.z);
        const float v1 = e1 * f1 * __int_as_float(m1.z);
        const float v2 = e2 * f2 * __int_as_float(m2.z);
        const float v3 = e3 * f3 * __int_as_float(m3.z);
        af += m0.w ? 0.f : v0;  ar += m0.w ? v0 : 0.f;
        af += m1.w ? 0.f : v1;  ar += m1.w ? v1 : 0.f;
        af += m2.w ? 0.f : v2;  ar += m2.w ? v2 : 0.f;
        af += m3.w ? 0.f : v3;  ar += m3.w ? v3 : 0.f;
    }
    for (; j < end; ++j) {
        const int4 m0 = meta[j];
        const float v0 = edge_feat[(size_t)m0.x * 64 + lane] *
                         node_feat[(size_t)m0.y * 64 + lane] *
                         __int_as_float(m0.z);
        af += m0.w ? 0.f : v0;
        ar += m0.w ? v0 : 0.f;
    }
    accF[(size_t)n * 64 + lane] = af;
    accR[(size_t)n * 64 + lane] = ar;
}

// ---------------------------------------------------------------------------
// Node kernel (R3-proven; aliasing-tolerant: reads -> barrier -> stores).
// ---------------------------------------------------------------------------
__global__ __launch_bounds__(256) void node_gemm_lds(
    const float* XF, const float* XR,
    const float* __restrict__ XN,
    const float* __restrict__ Wi, const float* __restrict__ Wo,
    const float* __restrict__ Wl, const float* __restrict__ loop_rel,
    const float* __restrict__ bias, float* C)
{
    __shared__ float Ws[192][64];
    const int tid = threadIdx.x;
    {
        const float4* wv;
        float4* sv = (float4*)&Ws[0][0];
        wv = (const float4*)Wi;
#pragma unroll
        for (int j = 0; j < 4; ++j) sv[tid + 256 * j] = wv[tid + 256 * j];
        wv = (const float4*)Wo;
#pragma unroll
        for (int j = 0; j < 4; ++j) sv[1024 + tid + 256 * j] = wv[tid + 256 * j];
        wv = (const float4*)Wl;
#pragma unroll
        for (int j = 0; j < 4; ++j) {
            const int f = tid + 256 * j;
            float4 v = wv[f];
            const float s = loop_rel[f >> 4];
            v.x *= s; v.y *= s; v.z *= s; v.w *= s;
            sv[2048 + f] = v;
        }
    }
    __syncthreads();

    const int tx = tid & 15;
    const int ty = tid >> 4;
    const size_t rbase = (size_t)blockIdx.x * 128 + 8 * ty;

    float acc[8][4] = {};
    const float* srcs[3] = { XF, XR, XN };
#pragma unroll
    for (int s = 0; s < 3; ++s) {
        const float* Xs = srcs[s];
#pragma unroll 2
        for (int kc = 0; kc < 16; ++kc) {
            float4 b[4];
#pragma unroll
            for (int kk = 0; kk < 4; ++kk)
                b[kk] = *(const float4*)&Ws[s * 64 + 4 * kc + kk][4 * tx];
#pragma unroll
            for (int i = 0; i < 8; ++i) {
                size_t r = rbase + (size_t)i;
                if (r >= NNODES) r = NNODES - 1;
                const float4 a = ((const float4*)(Xs + r * 64))[kc];
                acc[i][0] += a.x * b[0].x + a.y * b[1].x + a.z * b[2].x + a.w * b[3].x;
                acc[i][1] += a.x * b[0].y + a.y * b[1].y + a.z * b[2].y + a.w * b[3].y;
                acc[i][2] += a.x * b[0].z + a.y * b[1].z + a.z * b[2].z + a.w * b[3].z;
                acc[i][3] += a.x * b[0].w + a.y * b[1].w + a.z * b[2].w + a.w * b[3].w;
            }
        }
    }
    const float4 bb = *(const float4*)(bias + 4 * tx);
    __syncthreads();
#pragma unroll
    for (int i = 0; i < 8; ++i) {
        const size_t r = rbase + (size_t)i;
        if (r < NNODES) {
            float4 o;
            o.x = acc[i][0] * 0.3333333f + bb.x;
            o.y = acc[i][1] * 0.3333333f + bb.y;
            o.z = acc[i][2] * 0.3333333f + bb.z;
            o.w = acc[i][3] * 0.3333333f + bb.w;
            *(float4*)(C + r * 64 + 4 * tx) = o;
        }
    }
}

// ---------------------------------------------------------------------------
// Last-resort fallback scatter.
// ---------------------------------------------------------------------------
__global__ __launch_bounds__(256) void edge_scatter_kernel(
    const float* __restrict__ edge_feat,
    const float* __restrict__ node_feat,
    const float* __restrict__ edge_norm,
    const int*   __restrict__ src,
    const int*   __restrict__ dst,
    const int*   __restrict__ is_rev,
    float* __restrict__ accF,
    float* __restrict__ accR)
{
    const size_t t = (size_t)blockIdx.x * blockDim.x + threadIdx.x;
    if (t >= (size_t)NEDGES * 64) return;
    const int e    = (int)(t >> 6);
    const int lane = (int)(t & 63);
    const float ef   = edge_feat[(size_t)e * 64 + lane];
    const float comp = ef * node_feat[(size_t)src[e] * 64 + lane];
    float* accp = is_rev[e] ? accR : accF;
    unsafeAtomicAdd(accp + (size_t)dst[e] * 64 + lane, comp * edge_norm[e]);
}

// ---------------------------------------------------------------------------
extern "C" void kernel_launch(void* const* d_in, const int* in_sizes, int n_in,
                              void* d_out, int out_size, void* d_ws, size_t ws_size,
                              hipStream_t stream)
{
    const float* node_feat = (const float*)d_in[0];
    const float* edge_feat = (const float*)d_in[1];
    const float* edge_norm = (const float*)d_in[2];
    const int*   src       = (const int*)d_in[3];
    const int*   dst       = (const int*)d_in[4];
    const int*   is_rev    = (const int*)d_in[5];
    const float* in_w      = (const float*)d_in[6];
    const float* out_w     = (const float*)d_in[7];
    const float* rel_w     = (const float*)d_in[8];
    const float* loop_w    = (const float*)d_in[9];
    const float* loop_rel  = (const float*)d_in[10];
    const float* bias      = (const float*)d_in[11];

    float* node_out = (float*)d_out;
    float* edge_out = (float*)d_out + (size_t)NNODES * 64;

    const size_t accBytes = (size_t)NNODES * 64 * sizeof(float);
    const int edgeThreadBlocks = (NEDGES + 255) / 256;
    const int mfmaEdgeBlocks   = NEDGES / 256;               // 5000 (exact)
    const int f32EdgeBlocks    = (NEDGES + 127) / 128;       // 10000
    const int nodeGemmBlocks   = (NNODES + 127) / 128;       // 782
    const int aggBlocks        = (NNODES + 3) / 4;           // 25000

    // ws layout
    char* p = (char*)d_ws;
    unsigned short* wtb = (unsigned short*)p;  p += 64 * 64 * 2;   // 8 KB bf16 W^T
    int* cnt      = (int*)p;                 p += (size_t)NNODES * 4;
    int* excl     = (int*)p;                 p += (size_t)NNODES * 4;
    int* partials = (int*)p;                 p += 128 * 4;
    int* rowptr   = (int*)p;                 p += (size_t)(NNODES + 1) * 4;
    int* cursor   = (int*)p;                 p += (size_t)NNODES * 4;
    p = (char*)(((uintptr_t)p + 15) & ~(uintptr_t)15);
    int4* meta    = (int4*)p;                p += (size_t)NEDGES * 16;
    const size_t needed = (size_t)(p - (char*)d_ws);

    // accF borrows node_out (node_gemm_lds in-place safe);
    // accR borrows edge_out (overwritten afterwards by the edge GEMM).
    float* accF = node_out;
    float* accR = edge_out;

    if (ws_size >= needed) {
        // zero cnt (100000 ints = 25000 int4)
        k_zero<<<(25000 + 255) / 256, 256, 0, stream>>>((int4*)cnt, 25000);
        k_wprep<<<16, 256, 0, stream>>>(rel_w, wtb);
        k_count<<<edgeThreadBlocks, 256, 0, stream>>>(dst, cnt);
        k_scan1<<<NSCAN, 256, 0, stream>>>(cnt, excl, partials);
        k_scan2<<<1, 128, 0, stream>>>(partials, NSCAN);
        k_addback<<<(NNODES + 255) / 256, 256, 0, stream>>>(excl, partials, rowptr, cursor);
        k_scatter<<<edgeThreadBlocks, 256, 0, stream>>>(dst, src, edge_norm, is_rev, cursor, meta);
        k_agg<<<aggBlocks, 256, 0, stream>>>(edge_feat, node_feat, rowptr, meta, accF, accR);
        node_gemm_lds<<<nodeGemmBlocks, 256, 0, stream>>>(
            accF, accR, node_feat, in_w, out_w, loop_w, loop_rel, bias, node_out);
        mfma_edge_gemm<<<mfmaEdgeBlocks, 256, 0, stream>>>(edge_feat, wtb, edge_out);
    } else {
        // Atomic fallback with d_out borrowing (all-f32).
        hipMemsetAsync(d_out, 0, 2 * accBytes, stream);
        edge_scatter_kernel<<<(int)(((size_t)NEDGES * 64 + 255) / 256), 256, 0, stream>>>(
            edge_feat, node_feat, edge_norm, src, dst, is_rev, accF, accR);
        node_gemm_lds<<<nodeGemmBlocks, 256, 0, stream>>>(
            accF, accR, node_feat, in_w, out_w, loop_w, loop_rel, bias, node_out);
        edge_gemm_f32<<<f32EdgeBlocks, 256, 0, stream>>>(edge_feat, rel_w, edge_out);
    }
}

// Round 7
// 423.516 us; speedup vs baseline: 3.3682x; 1.1587x over previous
//
#include <hip/hip_runtime.h>

constexpr int NNODES = 100000;
constexpr int NEDGES = 1280000;
constexpr int SCAN_ELEMS = 1024;
constexpr int NSCAN = (NNODES + SCAN_ELEMS - 1) / SCAN_ELEMS;  // 98

typedef __attribute__((ext_vector_type(8))) short bf16x8;
typedef __attribute__((ext_vector_type(4))) float f32x4;

__device__ inline unsigned short f2bf(float x) {
    unsigned u = __float_as_uint(x);
    u += 0x7FFFu + ((u >> 16) & 1u);     // round-to-nearest-even
    return (unsigned short)(u >> 16);
}

// ---------------------------------------------------------------------------
// k_prep: blocks [0,64): build 4 bf16 transposed weight tables
//   wt[0]=rel_w^T, wt[1]=in_w^T, wt[2]=out_w^T, wt[3]=(diag(lr)@loop_w)^T
// blocks [64,162): zero the 400KB cnt array (int4 stores).
// ---------------------------------------------------------------------------
__global__ __launch_bounds__(256) void k_prep(
    const float* __restrict__ rel_w, const float* __restrict__ in_w,
    const float* __restrict__ out_w, const float* __restrict__ loop_w,
    const float* __restrict__ lr,
    unsigned short* __restrict__ wt,          // 4 * 4096
    int4* __restrict__ cnt4)                  // 25000
{
    if (blockIdx.x < 64) {
        const int t = blockIdx.x * 256 + threadIdx.x;   // [0, 16384)
        const int which = t >> 12;
        const int idx = t & 4095;
        const int k = idx >> 6, n = idx & 63;
        float v;
        if      (which == 0) v = rel_w[k * 64 + n];
        else if (which == 1) v = in_w[k * 64 + n];
        else if (which == 2) v = out_w[k * 64 + n];
        else                 v = loop_w[k * 64 + n] * lr[k];
        wt[which * 4096 + n * 64 + k] = f2bf(v);
    } else {
        const int i = (blockIdx.x - 64) * 256 + threadIdx.x;
        if (i < 25000) cnt4[i] = make_int4(0, 0, 0, 0);
    }
}

// ---------------------------------------------------------------------------
// MFMA edge GEMM (R5-validated): C[E,64] = X[E,64] @ W, X f32 -> bf16 in-reg.
// ---------------------------------------------------------------------------
__global__ __launch_bounds__(256) void mfma_edge_gemm(
    const float* __restrict__ X,
    const unsigned short* __restrict__ WT,   // [64 n][64 k] bf16
    float* __restrict__ C)
{
    const int lane = threadIdx.x & 63;
    const int wv   = threadIdx.x >> 6;
    const int R0   = blockIdx.x * 256 + wv * 64;
    const int lr   = lane & 15;
    const int lk8  = (lane >> 4) * 8;
    const int crow = (lane >> 4) * 4;

    bf16x8 fb[4][2];
#pragma unroll
    for (int nt = 0; nt < 4; ++nt)
#pragma unroll
        for (int ks = 0; ks < 2; ++ks)
            fb[nt][ks] = *(const bf16x8*)(WT + (size_t)(nt * 16 + lr) * 64 + ks * 32 + lk8);

    bf16x8 fa[4][2];
#pragma unroll
    for (int rt = 0; rt < 4; ++rt) {
        const float* xp = X + (size_t)(R0 + rt * 16 + lr) * 64 + lk8;
#pragma unroll
        for (int ks = 0; ks < 2; ++ks) {
            const float4 a0 = *(const float4*)(xp + ks * 32);
            const float4 a1 = *(const float4*)(xp + ks * 32 + 4);
            bf16x8 f;
            f[0] = (short)f2bf(a0.x); f[1] = (short)f2bf(a0.y);
            f[2] = (short)f2bf(a0.z); f[3] = (short)f2bf(a0.w);
            f[4] = (short)f2bf(a1.x); f[5] = (short)f2bf(a1.y);
            f[6] = (short)f2bf(a1.z); f[7] = (short)f2bf(a1.w);
            fa[rt][ks] = f;
        }
    }

#pragma unroll
    for (int rt = 0; rt < 4; ++rt) {
#pragma unroll
        for (int nt = 0; nt < 4; ++nt) {
            f32x4 acc = {0.f, 0.f, 0.f, 0.f};
            acc = __builtin_amdgcn_mfma_f32_16x16x32_bf16(fa[rt][0], fb[nt][0], acc, 0, 0, 0);
            acc = __builtin_amdgcn_mfma_f32_16x16x32_bf16(fa[rt][1], fb[nt][1], acc, 0, 0, 0);
            float* cp = C + (size_t)(R0 + rt * 16 + crow) * 64 + nt * 16 + lr;
            cp[0]   = acc[0];
            cp[64]  = acc[1];
            cp[128] = acc[2];
            cp[192] = acc[3];
        }
    }
}

// ---------------------------------------------------------------------------
// MFMA node GEMM: out = (AF@Wi + AR@Wo + NF@Wl')/3 + bias.
// AF/AR already bf16 (written by k_agg); NF converted in-reg.
// Same fragment geometry as mfma_edge_gemm; rows clamped/masked at N.
// ---------------------------------------------------------------------------
__global__ __launch_bounds__(256) void mfma_node_gemm(
    const unsigned short* __restrict__ AF,
    const unsigned short* __restrict__ AR,
    const float* __restrict__ NF,
    const unsigned short* __restrict__ WiT,
    const unsigned short* __restrict__ WoT,
    const unsigned short* __restrict__ WlT,
    const float* __restrict__ bias,
    float* __restrict__ out)
{
    const int lane = threadIdx.x & 63;
    const int wv   = threadIdx.x >> 6;
    const int R0   = blockIdx.x * 256 + wv * 64;
    const int lr   = lane & 15;
    const int lk8  = (lane >> 4) * 8;
    const int crow = (lane >> 4) * 4;

    bf16x8 bi[4][2], bo[4][2], bl[4][2];
#pragma unroll
    for (int nt = 0; nt < 4; ++nt)
#pragma unroll
        for (int ks = 0; ks < 2; ++ks) {
            const size_t off = (size_t)(nt * 16 + lr) * 64 + ks * 32 + lk8;
            bi[nt][ks] = *(const bf16x8*)(WiT + off);
            bo[nt][ks] = *(const bf16x8*)(WoT + off);
            bl[nt][ks] = *(const bf16x8*)(WlT + off);
        }
    float bb[4];
#pragma unroll
    for (int nt = 0; nt < 4; ++nt) bb[nt] = bias[nt * 16 + lr];

#pragma unroll
    for (int rt = 0; rt < 4; ++rt) {
        const int r = R0 + rt * 16 + lr;
        const size_t ra = (size_t)(r < NNODES ? r : NNODES - 1);

        bf16x8 aF[2], aR[2], aN[2];
#pragma unroll
        for (int ks = 0; ks < 2; ++ks) {
            aF[ks] = *(const bf16x8*)(AF + ra * 64 + ks * 32 + lk8);
            aR[ks] = *(const bf16x8*)(AR + ra * 64 + ks * 32 + lk8);
            const float4 a0 = *(const float4*)(NF + ra * 64 + ks * 32 + lk8);
            const float4 a1 = *(const float4*)(NF + ra * 64 + ks * 32 + lk8 + 4);
            bf16x8 f;
            f[0] = (short)f2bf(a0.x); f[1] = (short)f2bf(a0.y);
            f[2] = (short)f2bf(a0.z); f[3] = (short)f2bf(a0.w);
            f[4] = (short)f2bf(a1.x); f[5] = (short)f2bf(a1.y);
            f[6] = (short)f2bf(a1.z); f[7] = (short)f2bf(a1.w);
            aN[ks] = f;
        }

#pragma unroll
        for (int nt = 0; nt < 4; ++nt) {
            f32x4 acc = {0.f, 0.f, 0.f, 0.f};
            acc = __builtin_amdgcn_mfma_f32_16x16x32_bf16(aF[0], bi[nt][0], acc, 0, 0, 0);
            acc = __builtin_amdgcn_mfma_f32_16x16x32_bf16(aF[1], bi[nt][1], acc, 0, 0, 0);
            acc = __builtin_amdgcn_mfma_f32_16x16x32_bf16(aR[0], bo[nt][0], acc, 0, 0, 0);
            acc = __builtin_amdgcn_mfma_f32_16x16x32_bf16(aR[1], bo[nt][1], acc, 0, 0, 0);
            acc = __builtin_amdgcn_mfma_f32_16x16x32_bf16(aN[0], bl[nt][0], acc, 0, 0, 0);
            acc = __builtin_amdgcn_mfma_f32_16x16x32_bf16(aN[1], bl[nt][1], acc, 0, 0, 0);
#pragma unroll
            for (int i = 0; i < 4; ++i) {
                const int rr = R0 + rt * 16 + crow + i;
                if (rr < NNODES)
                    out[(size_t)rr * 64 + nt * 16 + lr] = acc[i] * 0.3333333f + bb[nt];
            }
        }
    }
}

// ---------------------------------------------------------------------------
// CSR build
// ---------------------------------------------------------------------------
__global__ __launch_bounds__(256) void k_count(const int* __restrict__ dst,
                                               int* __restrict__ cnt)
{
    const int e = blockIdx.x * 256 + threadIdx.x;
    if (e < NEDGES) atomicAdd(&cnt[dst[e]], 1);
}

__global__ __launch_bounds__(256) void k_scan1(const int* __restrict__ cnt,
                                               int* __restrict__ excl,
                                               int* __restrict__ partials)
{
    __shared__ int s[256];
    const int base = blockIdx.x * SCAN_ELEMS + threadIdx.x * 4;
    int v0 = 0, v1 = 0, v2 = 0, v3 = 0;
    if (base + 0 < NNODES) v0 = cnt[base + 0];
    if (base + 1 < NNODES) v1 = cnt[base + 1];
    if (base + 2 < NNODES) v2 = cnt[base + 2];
    if (base + 3 < NNODES) v3 = cnt[base + 3];
    const int tsum = v0 + v1 + v2 + v3;
    s[threadIdx.x] = tsum;
    __syncthreads();
    for (int off = 1; off < 256; off <<= 1) {
        const int t = (threadIdx.x >= off) ? s[threadIdx.x - off] : 0;
        __syncthreads();
        s[threadIdx.x] += t;
        __syncthreads();
    }
    const int texcl = s[threadIdx.x] - tsum;
    if (base + 0 < NNODES) excl[base + 0] = texcl;
    if (base + 1 < NNODES) excl[base + 1] = texcl + v0;
    if (base + 2 < NNODES) excl[base + 2] = texcl + v0 + v1;
    if (base + 3 < NNODES) excl[base + 3] = texcl + v0 + v1 + v2;
    if (threadIdx.x == 255) partials[blockIdx.x] = s[255];
}

// Fused: re-scan the 98 block partials in LDS, then add back. (No k_scan2.)
__global__ __launch_bounds__(256) void k_addback2(const int* __restrict__ excl,
                                                  const int* __restrict__ partials,
                                                  int* __restrict__ rowptr,
                                                  int* __restrict__ cursor)
{
    __shared__ int s[128];
    const int tid = threadIdx.x;
    int orig = 0;
    if (tid < 128) { orig = (tid < NSCAN) ? partials[tid] : 0; s[tid] = orig; }
    __syncthreads();
    for (int off = 1; off < 128; off <<= 1) {
        int t = 0;
        if (tid < 128 && tid >= off) t = s[tid - off];
        __syncthreads();
        if (tid < 128) s[tid] += t;
        __syncthreads();
    }
    if (tid < 128) s[tid] -= orig;    // inclusive -> exclusive
    __syncthreads();
    const int i = blockIdx.x * 256 + tid;
    if (i < NNODES) {
        const int v = excl[i] + s[i >> 10];
        rowptr[i] = v;
        cursor[i] = v;
    }
    if (i == 0) rowptr[NNODES] = NEDGES;
}

__global__ __launch_bounds__(256) void k_scatter(const int* __restrict__ dst,
                                                 const int* __restrict__ src,
                                                 const float* __restrict__ norm,
                                                 const int* __restrict__ is_rev,
                                                 int* __restrict__ cursor,
                                                 int4* __restrict__ meta)
{
    const int e = blockIdx.x * 256 + threadIdx.x;
    if (e >= NEDGES) return;
    const int d = dst[e];
    const int pos = atomicAdd(&cursor[d], 1);
    meta[pos] = make_int4(e, src[e], __float_as_int(norm[e]), is_rev[e]);
}

// ---------------------------------------------------------------------------
// Aggregation: one wave per node, bf16 accumulator output (feeds MFMA node
// GEMM directly; halves acc write traffic). Gathers stay f32 for precision.
// ---------------------------------------------------------------------------
__global__ __launch_bounds__(256) void k_agg(
    const float* __restrict__ edge_feat,
    const float* __restrict__ node_feat,
    const int*   __restrict__ rowptr,
    const int4*  __restrict__ meta,
    unsigned short* __restrict__ accF16,
    unsigned short* __restrict__ accR16)
{
    const int lane = threadIdx.x & 63;
    const int n    = (blockIdx.x * blockDim.x + threadIdx.x) >> 6;
    if (n >= NNODES) return;

    const int start = rowptr[n];
    const int end   = rowptr[n + 1];
    float af = 0.f, ar = 0.f;
    int j = start;
    for (; j + 3 < end; j += 4) {
        const int4 m0 = meta[j], m1 = meta[j + 1], m2 = meta[j + 2], m3 = meta[j + 3];
        const float e0 = edge_feat[(size_t)m0.x * 64 + lane];
        const float f0 = node_feat[(size_t)m0.y * 64 + lane];
        const float e1 = edge_feat[(size_t)m1.x * 64 + lane];
        const float f1 = node_feat[(size_t)m1.y * 64 + lane];
        const float e2 = edge_feat[(size_t)m2.x * 64 + lane];
        const float f2 = node_feat[(size_t)m2.y * 64 + lane];
        const float e3 = edge_feat[(size_t)m3.x * 64 + lane];
        const float f3 = node_feat[(size_t)m3.y * 64 + lane];
        const float v0 = e0 * f0 * __int_as_float(m0.z);
        const float v1 = e1 * f1 * __int_as_float(m1.z);
        const float v2 = e2 * f2 * __int_as_float(m2.z);
        const float v3 = e3 * f3 * __int_as_float(m3.z);
        af += m0.w ? 0.f : v0;  ar += m0.w ? v0 : 0.f;
        af += m1.w ? 0.f : v1;  ar += m1.w ? v1 : 0.f;
        af += m2.w ? 0.f : v2;  ar += m2.w ? v2 : 0.f;
        af += m3.w ? 0.f : v3;  ar += m3.w ? v3 : 0.f;
    }
    for (; j < end; ++j) {
        const int4 m0 = meta[j];
        const float v0 = edge_feat[(size_t)m0.x * 64 + lane] *
                         node_feat[(size_t)m0.y * 64 + lane] *
                         __int_as_float(m0.z);
        af += m0.w ? 0.f : v0;
        ar += m0.w ? v0 : 0.f;
    }
    accF16[(size_t)n * 64 + lane] = f2bf(af);
    accR16[(size_t)n * 64 + lane] = f2bf(ar);
}

// ---------------------------------------------------------------------------
// Fallback path kernels (ws too small): R3-proven all-f32 pipeline.
// ---------------------------------------------------------------------------
__global__ __launch_bounds__(256) void edge_scatter_kernel(
    const float* __restrict__ edge_feat,
    const float* __restrict__ node_feat,
    const float* __restrict__ edge_norm,
    const int*   __restrict__ src,
    const int*   __restrict__ dst,
    const int*   __restrict__ is_rev,
    float* __restrict__ accF,
    float* __restrict__ accR)
{
    const size_t t = (size_t)blockIdx.x * blockDim.x + threadIdx.x;
    if (t >= (size_t)NEDGES * 64) return;
    const int e    = (int)(t >> 6);
    const int lane = (int)(t & 63);
    const float ef   = edge_feat[(size_t)e * 64 + lane];
    const float comp = ef * node_feat[(size_t)src[e] * 64 + lane];
    float* accp = is_rev[e] ? accR : accF;
    unsafeAtomicAdd(accp + (size_t)dst[e] * 64 + lane, comp * edge_norm[e]);
}

__global__ __launch_bounds__(256) void node_gemm_lds(
    const float* XF, const float* XR,
    const float* __restrict__ XN,
    const float* __restrict__ Wi, const float* __restrict__ Wo,
    const float* __restrict__ Wl, const float* __restrict__ loop_rel,
    const float* __restrict__ bias, float* C)
{
    __shared__ float Ws[192][64];
    const int tid = threadIdx.x;
    {
        const float4* wv;
        float4* sv = (float4*)&Ws[0][0];
        wv = (const float4*)Wi;
#pragma unroll
        for (int j = 0; j < 4; ++j) sv[tid + 256 * j] = wv[tid + 256 * j];
        wv = (const float4*)Wo;
#pragma unroll
        for (int j = 0; j < 4; ++j) sv[1024 + tid + 256 * j] = wv[tid + 256 * j];
        wv = (const float4*)Wl;
#pragma unroll
        for (int j = 0; j < 4; ++j) {
            const int f = tid + 256 * j;
            float4 v = wv[f];
            const float s = loop_rel[f >> 4];
            v.x *= s; v.y *= s; v.z *= s; v.w *= s;
            sv[2048 + f] = v;
        }
    }
    __syncthreads();

    const int tx = tid & 15;
    const int ty = tid >> 4;
    const size_t rbase = (size_t)blockIdx.x * 128 + 8 * ty;

    float acc[8][4] = {};
    const float* srcs[3] = { XF, XR, XN };
#pragma unroll
    for (int s = 0; s < 3; ++s) {
        const float* Xs = srcs[s];
#pragma unroll 2
        for (int kc = 0; kc < 16; ++kc) {
            float4 b[4];
#pragma unroll
            for (int kk = 0; kk < 4; ++kk)
                b[kk] = *(const float4*)&Ws[s * 64 + 4 * kc + kk][4 * tx];
#pragma unroll
            for (int i = 0; i < 8; ++i) {
                size_t r = rbase + (size_t)i;
                if (r >= NNODES) r = NNODES - 1;
                const float4 a = ((const float4*)(Xs + r * 64))[kc];
                acc[i][0] += a.x * b[0].x + a.y * b[1].x + a.z * b[2].x + a.w * b[3].x;
                acc[i][1] += a.x * b[0].y + a.y * b[1].y + a.z * b[2].y + a.w * b[3].y;
                acc[i][2] += a.x * b[0].z + a.y * b[1].z + a.z * b[2].z + a.w * b[3].z;
                acc[i][3] += a.x * b[0].w + a.y * b[1].w + a.z * b[2].w + a.w * b[3].w;
            }
        }
    }
    const float4 bb = *(const float4*)(bias + 4 * tx);
    __syncthreads();
#pragma unroll
    for (int i = 0; i < 8; ++i) {
        const size_t r = rbase + (size_t)i;
        if (r < NNODES) {
            float4 o;
            o.x = acc[i][0] * 0.3333333f + bb.x;
            o.y = acc[i][1] * 0.3333333f + bb.y;
            o.z = acc[i][2] * 0.3333333f + bb.z;
            o.w = acc[i][3] * 0.3333333f + bb.w;
            *(float4*)(C + r * 64 + 4 * tx) = o;
        }
    }
}

__global__ __launch_bounds__(256) void edge_gemm_f32(
    const float* __restrict__ X,
    const float* __restrict__ W,
    float* __restrict__ C)
{
    __shared__ float Ws[64][64];
    const int tid = threadIdx.x;
    {
        const float4* Wv = (const float4*)W;
        float4* Sv = (float4*)&Ws[0][0];
#pragma unroll
        for (int j = 0; j < 4; ++j) Sv[tid + 256 * j] = Wv[tid + 256 * j];
    }
    __syncthreads();

    const int tx = tid & 15;
    const int ty = tid >> 4;
    const size_t rbase = (size_t)blockIdx.x * 128 + 8 * ty;
    const float* Xp = X + rbase * 64;

    float acc[8][4] = {};
#pragma unroll 2
    for (int kc = 0; kc < 16; ++kc) {
        float4 b[4];
#pragma unroll
        for (int kk = 0; kk < 4; ++kk)
            b[kk] = *(const float4*)&Ws[4 * kc + kk][4 * tx];
#pragma unroll
        for (int i = 0; i < 8; ++i) {
            const float4 a = ((const float4*)(Xp + (size_t)i * 64))[kc];
            acc[i][0] += a.x * b[0].x + a.y * b[1].x + a.z * b[2].x + a.w * b[3].x;
            acc[i][1] += a.x * b[0].y + a.y * b[1].y + a.z * b[2].y + a.w * b[3].y;
            acc[i][2] += a.x * b[0].z + a.y * b[1].z + a.z * b[2].z + a.w * b[3].z;
            acc[i][3] += a.x * b[0].w + a.y * b[1].w + a.z * b[2].w + a.w * b[3].w;
        }
    }
#pragma unroll
    for (int i = 0; i < 8; ++i) {
        float4 o = make_float4(acc[i][0], acc[i][1], acc[i][2], acc[i][3]);
        *(float4*)(C + (rbase + (size_t)i) * 64 + 4 * tx) = o;
    }
}

// ---------------------------------------------------------------------------
extern "C" void kernel_launch(void* const* d_in, const int* in_sizes, int n_in,
                              void* d_out, int out_size, void* d_ws, size_t ws_size,
                              hipStream_t stream)
{
    const float* node_feat = (const float*)d_in[0];
    const float* edge_feat = (const float*)d_in[1];
    const float* edge_norm = (const float*)d_in[2];
    const int*   src       = (const int*)d_in[3];
    const int*   dst       = (const int*)d_in[4];
    const int*   is_rev    = (const int*)d_in[5];
    const float* in_w      = (const float*)d_in[6];
    const float* out_w     = (const float*)d_in[7];
    const float* rel_w     = (const float*)d_in[8];
    const float* loop_w    = (const float*)d_in[9];
    const float* loop_rel  = (const float*)d_in[10];
    const float* bias      = (const float*)d_in[11];

    float* node_out = (float*)d_out;
    float* edge_out = (float*)d_out + (size_t)NNODES * 64;

    const size_t accBytes = (size_t)NNODES * 64 * sizeof(float);
    const int edgeThreadBlocks = (NEDGES + 255) / 256;
    const int mfmaEdgeBlocks   = NEDGES / 256;               // 5000 (exact)
    const int mfmaNodeBlocks   = (NNODES + 255) / 256;       // 391
    const int f32EdgeBlocks    = (NEDGES + 127) / 128;
    const int nodeLdsBlocks    = (NNODES + 127) / 128;
    const int aggBlocks        = (NNODES + 3) / 4;           // 25000

    // ws layout
    char* p = (char*)d_ws;
    unsigned short* wt = (unsigned short*)p;  p += 4 * 4096 * 2;  // 32 KB: rel,Wi,Wo,Wl'
    int* cnt      = (int*)p;                 p += (size_t)NNODES * 4;
    int* excl     = (int*)p;                 p += (size_t)NNODES * 4;
    int* partials = (int*)p;                 p += 128 * 4;
    int* rowptr   = (int*)p;                 p += (size_t)(NNODES + 1) * 4;
    int* cursor   = (int*)p;                 p += (size_t)NNODES * 4;
    p = (char*)(((uintptr_t)p + 15) & ~(uintptr_t)15);
    int4* meta    = (int4*)p;                p += (size_t)NEDGES * 16;
    unsigned short* accF16 = (unsigned short*)p;  p += (size_t)NNODES * 64 * 2;
    unsigned short* accR16 = (unsigned short*)p;  p += (size_t)NNODES * 64 * 2;
    const size_t needed = (size_t)(p - (char*)d_ws);

    if (ws_size >= needed) {
        k_prep<<<162, 256, 0, stream>>>(rel_w, in_w, out_w, loop_w, loop_rel,
                                        wt, (int4*)cnt);
        k_count<<<edgeThreadBlocks, 256, 0, stream>>>(dst, cnt);
        k_scan1<<<NSCAN, 256, 0, stream>>>(cnt, excl, partials);
        k_addback2<<<(NNODES + 255) / 256, 256, 0, stream>>>(excl, partials, rowptr, cursor);
        k_scatter<<<edgeThreadBlocks, 256, 0, stream>>>(dst, src, edge_norm, is_rev, cursor, meta);
        k_agg<<<aggBlocks, 256, 0, stream>>>(edge_feat, node_feat, rowptr, meta, accF16, accR16);
        mfma_node_gemm<<<mfmaNodeBlocks, 256, 0, stream>>>(
            accF16, accR16, node_feat,
            wt + 4096, wt + 2 * 4096, wt + 3 * 4096, bias, node_out);
        mfma_edge_gemm<<<mfmaEdgeBlocks, 256, 0, stream>>>(edge_feat, wt, edge_out);
    } else {
        // Atomic fallback with d_out borrowing (all-f32).
        float* accF = node_out;
        float* accR = edge_out;
        hipMemsetAsync(d_out, 0, 2 * accBytes, stream);
        edge_scatter_kernel<<<(int)(((size_t)NEDGES * 64 + 255) / 256), 256, 0, stream>>>(
            edge_feat, node_feat, edge_norm, src, dst, is_rev, accF, accR);
        node_gemm_lds<<<nodeLdsBlocks, 256, 0, stream>>>(
            accF, accR, node_feat, in_w, out_w, loop_w, loop_rel, bias, node_out);
        edge_gemm_f32<<<f32EdgeBlocks, 256, 0, stream>>>(edge_feat, rel_w, edge_out);
    }
}